// Round 3
// baseline (6232.516 us; speedup 1.0000x reference)
//
#include <hip/hip_runtime.h>

#define NBATCH 128
#define NDIM 512
static constexpr size_t MAT = (size_t)NDIM * NDIM;      // 262144
static constexpr size_t BATMAT = (size_t)NBATCH * MAT;  // 33554432 floats
#define SIGMA_F 1e-6f

// =====================================================================
// GEMM 128x128 tile, 8x8 per thread: C[i][j] = alpha*sum_k OpA(k,i)*OpB(k,j)
//   OpA(k,i) = TA ? A[i*N+k] : A[k*N+i]
//   OpB(k,j) = TB ? B[j*N+k] : B[k*N+j]
// grid (4,4,NBATCH), 256 threads.
// =====================================================================
template <int TA, int TB>
__global__ __launch_bounds__(256) void gemm512b(const float* __restrict__ Ag,
                                                const float* __restrict__ Bg,
                                                float* __restrict__ Cg,
                                                const float* __restrict__ alphaPtr) {
  const int b = blockIdx.z;
  const float* Ab = Ag + (size_t)b * MAT;
  const float* Bb = Bg + (size_t)b * MAT;
  float* Cb = Cg + (size_t)b * MAT;
  const int i0 = blockIdx.y * 128, j0 = blockIdx.x * 128;
  __shared__ float As[32][132];
  __shared__ float Bs[32][132];
  const int tid = threadIdx.x;
  const int tx = tid & 15, ty = tid >> 4;
  float acc[2][2][4][4] = {};
  for (int k0 = 0; k0 < NDIM; k0 += 32) {
    if (TA == 0) {
      const int kk = tid >> 5, c4 = (tid & 31) << 2;
#pragma unroll
      for (int pp = 0; pp < 4; ++pp) {
        float4 v = *reinterpret_cast<const float4*>(&Ab[(size_t)(k0 + kk + 8 * pp) * NDIM + i0 + c4]);
        *reinterpret_cast<float4*>(&As[kk + 8 * pp][c4]) = v;
      }
    } else {
      const int m = tid >> 3, kq = (tid & 7) << 2;
#pragma unroll
      for (int pp = 0; pp < 4; ++pp) {
        float4 v = *reinterpret_cast<const float4*>(&Ab[(size_t)(i0 + m + 32 * pp) * NDIM + k0 + kq]);
        As[kq + 0][m + 32 * pp] = v.x;
        As[kq + 1][m + 32 * pp] = v.y;
        As[kq + 2][m + 32 * pp] = v.z;
        As[kq + 3][m + 32 * pp] = v.w;
      }
    }
    if (TB == 0) {
      const int kk = tid >> 5, c4 = (tid & 31) << 2;
#pragma unroll
      for (int pp = 0; pp < 4; ++pp) {
        float4 v = *reinterpret_cast<const float4*>(&Bb[(size_t)(k0 + kk + 8 * pp) * NDIM + j0 + c4]);
        *reinterpret_cast<float4*>(&Bs[kk + 8 * pp][c4]) = v;
      }
    } else {
      const int m = tid >> 3, kq = (tid & 7) << 2;
#pragma unroll
      for (int pp = 0; pp < 4; ++pp) {
        float4 v = *reinterpret_cast<const float4*>(&Bb[(size_t)(j0 + m + 32 * pp) * NDIM + k0 + kq]);
        Bs[kq + 0][m + 32 * pp] = v.x;
        Bs[kq + 1][m + 32 * pp] = v.y;
        Bs[kq + 2][m + 32 * pp] = v.z;
        Bs[kq + 3][m + 32 * pp] = v.w;
      }
    }
    __syncthreads();
#pragma unroll
    for (int kk = 0; kk < 32; ++kk) {
      float4 a0 = *reinterpret_cast<const float4*>(&As[kk][ty << 2]);
      float4 a1 = *reinterpret_cast<const float4*>(&As[kk][64 + (ty << 2)]);
      float4 b0 = *reinterpret_cast<const float4*>(&Bs[kk][tx << 2]);
      float4 b1 = *reinterpret_cast<const float4*>(&Bs[kk][64 + (tx << 2)]);
      const float ar[2][4] = {{a0.x, a0.y, a0.z, a0.w}, {a1.x, a1.y, a1.z, a1.w}};
      const float br[2][4] = {{b0.x, b0.y, b0.z, b0.w}, {b1.x, b1.y, b1.z, b1.w}};
#pragma unroll
      for (int ri = 0; ri < 2; ++ri)
#pragma unroll
        for (int ci = 0; ci < 2; ++ci)
#pragma unroll
          for (int r = 0; r < 4; ++r)
#pragma unroll
            for (int c = 0; c < 4; ++c)
              acc[ri][ci][r][c] += ar[ri][r] * br[ci][c];
    }
    __syncthreads();
  }
  const float alpha = alphaPtr ? alphaPtr[b] : 1.0f;
#pragma unroll
  for (int ri = 0; ri < 2; ++ri)
#pragma unroll
    for (int r = 0; r < 4; ++r) {
      const int gi = i0 + ri * 64 + (ty << 2) + r;
#pragma unroll
      for (int ci = 0; ci < 2; ++ci) {
        float4 o = make_float4(alpha * acc[ri][ci][r][0], alpha * acc[ri][ci][r][1],
                               alpha * acc[ri][ci][r][2], alpha * acc[ri][ci][r][3]);
        *reinterpret_cast<float4*>(&Cb[(size_t)gi * NDIM + j0 + ci * 64 + (tx << 2)]) = o;
      }
    }
}

// =====================================================================
// rho[b] = clip( ||Q||_F / ||ATA||_F , 1e-6, 1e6 )
// =====================================================================
__global__ __launch_bounds__(512) void norms_rho(const float* __restrict__ Q,
                                                 const float* __restrict__ ATA,
                                                 float* __restrict__ rho) {
  const int b = blockIdx.x;
  const int tid = threadIdx.x;
  const float* Qb = Q + (size_t)b * MAT;
  const float* Tb = ATA + (size_t)b * MAT;
  double sq = 0.0, st = 0.0;
  for (int e = tid; e < (int)MAT; e += 512) {
    float q = Qb[e];
    float t = Tb[e];
    sq += (double)q * q;
    st += (double)t * t;
  }
  __shared__ double s1[512];
  __shared__ double s2[512];
  s1[tid] = sq;
  s2[tid] = st;
  __syncthreads();
  for (int h = 256; h > 0; h >>= 1) {
    if (tid < h) {
      s1[tid] += s1[tid + h];
      s2[tid] += s2[tid + h];
    }
    __syncthreads();
  }
  if (tid == 0) {
    double r = sqrt(s1[0]) / sqrt(s2[0]);
    r = fmin(fmax(r, 1e-6), 1e6);
    rho[b] = (float)r;
  }
}

// =====================================================================
// M = Q + rho*ATA + sigma*I   (in place on the ATA buffer)
// =====================================================================
__global__ void form_m(const float* __restrict__ Q, const float* __restrict__ rho,
                       float* __restrict__ M) {
  size_t stride = (size_t)gridDim.x * blockDim.x;
  for (size_t e = (size_t)blockIdx.x * blockDim.x + threadIdx.x; e < BATMAT; e += stride) {
    int b = (int)(e >> 18);
    int ij = (int)(e & (MAT - 1));
    int i = ij >> 9, j = ij & 511;
    float v = Q[e] + rho[b] * M[e];
    if (i == j) v += SIGMA_F;
    M[e] = v;
  }
}

// =====================================================================
// Blocked Cholesky, NB=64: per step p, (1) factor diag block + trsm the
// panel below it (one block per batch), (2) parallel trailing syrk.
// =====================================================================
__global__ __launch_bounds__(256) void chol_diag_panel(float* __restrict__ Mg, int p) {
  float* M = Mg + (size_t)blockIdx.x * MAT;
  const int k0 = p * 64;
  __shared__ float D[64][65];
  __shared__ float Di[64][65];
  __shared__ float U[64][65];
  const int tid = threadIdx.x;
  for (int e = tid; e < 4096; e += 256) {
    int r = e >> 6, c = e & 63;
    D[r][c] = M[(size_t)(k0 + r) * NDIM + k0 + c];
  }
  __syncthreads();
  // factor D = L_d L_d^T (lower)
  for (int j = 0; j < 64; ++j) {
    if (tid == 0) D[j][j] = sqrtf(D[j][j]);
    __syncthreads();
    if (tid > j && tid < 64) D[tid][j] /= D[j][j];
    __syncthreads();
    for (int e = tid; e < 4096; e += 256) {
      int r = e >> 6, c = e & 63;
      if (r > j && c > j && c <= r) D[r][c] -= D[r][j] * D[c][j];
    }
    __syncthreads();
  }
  // store L_d lower back
  for (int e = tid; e < 4096; e += 256) {
    int r = e >> 6, c = e & 63;
    if (c <= r) M[(size_t)(k0 + r) * NDIM + k0 + c] = D[r][c];
  }
  // Dinv = L_d^{-1} (lower), thread-per-column
  if (tid < 64) {
    const int j = tid;
    for (int ii = j; ii < 64; ++ii) {
      float v = (ii == j) ? 1.f : 0.f;
      for (int m = j; m < ii; ++m) v -= D[ii][m] * Di[m][j];
      Di[ii][j] = v / D[ii][ii];
    }
  }
  __syncthreads();
  // panel: L[i,p] = M[i,p] * Dinv^T
  for (int i0 = k0 + 64; i0 < NDIM; i0 += 64) {
    for (int e = tid; e < 4096; e += 256) {
      int r = e >> 6, c = e & 63;
      U[r][c] = M[(size_t)(i0 + r) * NDIM + k0 + c];
    }
    __syncthreads();
    for (int e = tid; e < 4096; e += 256) {
      int r = e >> 6, j = e & 63;
      float s = 0.f;
      for (int m = 0; m <= j; ++m) s += U[r][m] * Di[j][m];
      M[(size_t)(i0 + r) * NDIM + k0 + j] = s;
    }
    __syncthreads();
  }
}

// trailing update: M[I,J] -= L[I,p] L[J,p]^T, one 64x64 tile per block.
// grid (npairs, NBATCH)
__global__ __launch_bounds__(256) void chol_syrk(float* __restrict__ Mg, int p) {
  float* M = Mg + (size_t)blockIdx.y * MAT;
  const int k0 = p * 64;
  int t = blockIdx.x;
  int ti = 0;
  while ((ti + 1) * (ti + 2) / 2 <= t) ++ti;
  const int tj = t - ti * (ti + 1) / 2;
  const int I0 = k0 + 64 + ti * 64;
  const int J0 = k0 + 64 + tj * 64;
  __shared__ float LI[64][68];  // LI[m][r] = L[I0+r][k0+m]
  __shared__ float LJ[64][68];
  const int tid = threadIdx.x;
  {
    const int r = tid >> 2, mq = (tid & 3) << 4;
#pragma unroll
    for (int q = 0; q < 4; ++q) {
      float4 v = *reinterpret_cast<const float4*>(&M[(size_t)(I0 + r) * NDIM + k0 + mq + q * 4]);
      LI[mq + q * 4 + 0][r] = v.x;
      LI[mq + q * 4 + 1][r] = v.y;
      LI[mq + q * 4 + 2][r] = v.z;
      LI[mq + q * 4 + 3][r] = v.w;
      float4 w = *reinterpret_cast<const float4*>(&M[(size_t)(J0 + r) * NDIM + k0 + mq + q * 4]);
      LJ[mq + q * 4 + 0][r] = w.x;
      LJ[mq + q * 4 + 1][r] = w.y;
      LJ[mq + q * 4 + 2][r] = w.z;
      LJ[mq + q * 4 + 3][r] = w.w;
    }
  }
  __syncthreads();
  const int tx = tid & 15, ty = tid >> 4;
  float acc[4][4] = {};
#pragma unroll 16
  for (int m = 0; m < 64; ++m) {
    float4 a = *reinterpret_cast<const float4*>(&LI[m][ty << 2]);
    float4 bv = *reinterpret_cast<const float4*>(&LJ[m][tx << 2]);
    acc[0][0] += a.x * bv.x; acc[0][1] += a.x * bv.y; acc[0][2] += a.x * bv.z; acc[0][3] += a.x * bv.w;
    acc[1][0] += a.y * bv.x; acc[1][1] += a.y * bv.y; acc[1][2] += a.y * bv.z; acc[1][3] += a.y * bv.w;
    acc[2][0] += a.z * bv.x; acc[2][1] += a.z * bv.y; acc[2][2] += a.z * bv.z; acc[2][3] += a.z * bv.w;
    acc[3][0] += a.w * bv.x; acc[3][1] += a.w * bv.y; acc[3][2] += a.w * bv.z; acc[3][3] += a.w * bv.w;
  }
#pragma unroll
  for (int r = 0; r < 4; ++r) {
    float4 cur = *reinterpret_cast<const float4*>(&M[(size_t)(I0 + (ty << 2) + r) * NDIM + J0 + (tx << 2)]);
    cur.x -= acc[r][0];
    cur.y -= acc[r][1];
    cur.z -= acc[r][2];
    cur.w -= acc[r][3];
    *reinterpret_cast<float4*>(&M[(size_t)(I0 + (ty << 2) + r) * NDIM + J0 + (tx << 2)]) = cur;
  }
}

// =====================================================================
// Triangular inverse W = L^{-1} (lower).
// =====================================================================
__global__ __launch_bounds__(256) void trinv_diag(const float* __restrict__ Lg,
                                                  float* __restrict__ Wg) {
  const int b = blockIdx.x;
  const float* L = Lg + (size_t)b * MAT;
  float* W = Wg + (size_t)b * MAT;
  __shared__ float Ld[8][32][33];
  __shared__ float Wd[8][32][33];
  const int g = threadIdx.x >> 5, l = threadIdx.x & 31;
  for (int pass = 0; pass < 2; ++pass) {
    const int bi = pass * 8 + g;
    const int o = bi * 32;
    for (int q = 0; q < 32; ++q) Ld[g][q][l] = L[(size_t)(o + q) * NDIM + o + l];
    __syncthreads();
    for (int ii = l; ii < 32; ++ii) {
      float v = (ii == l) ? 1.f : 0.f;
      for (int m = l; m < ii; ++m) v -= Ld[g][ii][m] * Wd[g][m][l];
      Wd[g][ii][l] = v / Ld[g][ii][ii];
    }
    __syncthreads();
    for (int q = 0; q < 32; ++q)
      if (l <= q) W[(size_t)(o + q) * NDIM + o + l] = Wd[g][q][l];
    __syncthreads();
  }
}

__global__ __launch_bounds__(256) void trinv_offdiag(const float* __restrict__ Lg,
                                                     float* __restrict__ Wg) {
  const int J = blockIdx.x;
  const int b = blockIdx.y;
  const float* L = Lg + (size_t)b * MAT;
  float* W = Wg + (size_t)b * MAT;
  __shared__ float Ls[32][33];
  __shared__ float Ws[32][33];
  __shared__ float Ts[32][33];
  __shared__ float Wi[32][33];
  const int tid = threadIdx.x;
  const int r = tid >> 3, c0 = (tid & 7) << 2;
  for (int I = J + 1; I < 16; ++I) {
    float acc[4] = {0.f, 0.f, 0.f, 0.f};
    for (int K = J; K < I; ++K) {
      __syncthreads();
      for (int e = tid; e < 1024; e += 256) {
        int rr = e >> 5, cc = e & 31;
        Ls[rr][cc] = L[(size_t)(I * 32 + rr) * NDIM + K * 32 + cc];
        Ws[rr][cc] = W[(size_t)(K * 32 + rr) * NDIM + J * 32 + cc];
      }
      __syncthreads();
#pragma unroll 8
      for (int m = 0; m < 32; ++m) {
        float lv = Ls[r][m];
        acc[0] += lv * Ws[m][c0 + 0];
        acc[1] += lv * Ws[m][c0 + 1];
        acc[2] += lv * Ws[m][c0 + 2];
        acc[3] += lv * Ws[m][c0 + 3];
      }
    }
    __syncthreads();
    Ts[r][c0 + 0] = acc[0];
    Ts[r][c0 + 1] = acc[1];
    Ts[r][c0 + 2] = acc[2];
    Ts[r][c0 + 3] = acc[3];
    for (int e = tid; e < 1024; e += 256) {
      int rr = e >> 5, cc = e & 31;
      Wi[rr][cc] = W[(size_t)(I * 32 + rr) * NDIM + I * 32 + cc];
    }
    __syncthreads();
    float o0 = 0.f, o1 = 0.f, o2 = 0.f, o3 = 0.f;
#pragma unroll 8
    for (int m = 0; m < 32; ++m) {
      float wv = Wi[r][m];
      o0 += wv * Ts[m][c0 + 0];
      o1 += wv * Ts[m][c0 + 1];
      o2 += wv * Ts[m][c0 + 2];
      o3 += wv * Ts[m][c0 + 3];
    }
    W[(size_t)(I * 32 + r) * NDIM + J * 32 + c0 + 0] = -o0;
    W[(size_t)(I * 32 + r) * NDIM + J * 32 + c0 + 1] = -o1;
    W[(size_t)(I * 32 + r) * NDIM + J * 32 + c0 + 2] = -o2;
    W[(size_t)(I * 32 + r) * NDIM + J * 32 + c0 + 3] = -o3;
    __syncthreads();
  }
}

// =====================================================================
// c = -Minv * p
// =====================================================================
__global__ __launch_bounds__(512) void cvec_kernel(const float* __restrict__ Minv,
                                                   const float* __restrict__ p,
                                                   float* __restrict__ c) {
  const int b = blockIdx.x, i = threadIdx.x;
  __shared__ float ps[512];
  ps[i] = p[b * NDIM + i];
  __syncthreads();
  const float* Mb = Minv + (size_t)b * MAT;
  float acc = 0.f;
#pragma unroll 8
  for (int m = 0; m < NDIM; ++m) acc += Mb[m * NDIM + i] * ps[m];
  c[b * NDIM + i] = -acc;
}

// =====================================================================
// d = A * c   (wave row-dots)
// =====================================================================
__global__ __launch_bounds__(512) void dvec_kernel(const float* __restrict__ Ain,
                                                   const float* __restrict__ c,
                                                   float* __restrict__ d) {
  const int b = blockIdx.x, i = threadIdx.x;
  __shared__ float cs[512];
  cs[i] = c[b * NDIM + i];
  __syncthreads();
  const int wv = i >> 6, ln = i & 63;
  const float* Ab = Ain + (size_t)b * MAT;
  for (int q = 0; q < 64; ++q) {
    const int j = wv * 64 + q;
    const float* Arow = Ab + (size_t)j * NDIM;
    float s = 0.f;
#pragma unroll
    for (int h = 0; h < 8; ++h) s += Arow[h * 64 + ln] * cs[h * 64 + ln];
    for (int off = 32; off > 0; off >>= 1) s += __shfl_down(s, off);
    if (ln == 0) d[b * NDIM + j] = s;
  }
}

// =====================================================================
// One ADMM iteration in y-space:  y = d + S'w;  z=clip(y+u); u+=y-z; w=z-u
// grid: 256 blocks (2 per batch, j-halved), 512 threads.
// =====================================================================
__global__ __launch_bounds__(512) void admm_step(const float* __restrict__ S,
                                                 const float* __restrict__ dvec,
                                                 const float* __restrict__ lb,
                                                 const float* __restrict__ ub,
                                                 float* __restrict__ wbuf,
                                                 float* __restrict__ ubuf) {
  const int blk = blockIdx.x;
  const int b = blk >> 1, h = blk & 1;
  const int t = threadIdx.x;
  __shared__ float ws_s[512];
  __shared__ float4 part[512];
  ws_s[t] = wbuf[b * NDIM + t];
  __syncthreads();
  const int j4 = t & 63;
  const int ks = t >> 6;
  const float4* Srow = reinterpret_cast<const float4*>(S + (size_t)b * MAT) +
                       (size_t)(ks * 64) * 128 + h * 64 + j4;
  float4 acc = make_float4(0.f, 0.f, 0.f, 0.f);
#pragma unroll 8
  for (int k = 0; k < 64; ++k) {
    float w = ws_s[ks * 64 + k];
    float4 s = Srow[(size_t)k * 128];
    acc.x += s.x * w;
    acc.y += s.y * w;
    acc.z += s.z * w;
    acc.w += s.w * w;
  }
  part[t] = acc;
  __syncthreads();
  if (t < 64) {
    float4 y = part[t];
#pragma unroll
    for (int s = 1; s < 8; ++s) {
      float4 q = part[s * 64 + t];
      y.x += q.x; y.y += q.y; y.z += q.z; y.w += q.w;
    }
    const size_t off = (size_t)b * NDIM + h * 256 + t * 4;
    float4 dv = *reinterpret_cast<const float4*>(dvec + off);
    float4 uv = *reinterpret_cast<const float4*>(ubuf + off);
    float4 lbv = *reinterpret_cast<const float4*>(lb + off);
    float4 ubv = *reinterpret_cast<const float4*>(ub + off);
    y.x += dv.x; y.y += dv.y; y.z += dv.z; y.w += dv.w;
    float4 zv, wv;
    zv.x = fminf(fmaxf(y.x + uv.x, lbv.x), ubv.x);
    zv.y = fminf(fmaxf(y.y + uv.y, lbv.y), ubv.y);
    zv.z = fminf(fmaxf(y.z + uv.z, lbv.z), ubv.z);
    zv.w = fminf(fmaxf(y.w + uv.w, lbv.w), ubv.w);
    uv.x += y.x - zv.x; uv.y += y.y - zv.y; uv.z += y.z - zv.z; uv.w += y.w - zv.w;
    wv.x = zv.x - uv.x; wv.y = zv.y - uv.y; wv.z = zv.z - uv.z; wv.w = zv.w - uv.w;
    *reinterpret_cast<float4*>(ubuf + off) = uv;
    *reinterpret_cast<float4*>(wbuf + off) = wv;
  }
}

// =====================================================================
// x = c + P1^T w
// =====================================================================
__global__ __launch_bounds__(512) void final_x(const float* __restrict__ P1,
                                               const float* __restrict__ c,
                                               const float* __restrict__ w,
                                               float* __restrict__ out) {
  const int b = blockIdx.x, i = threadIdx.x;
  __shared__ float ws_s[512];
  ws_s[i] = w[b * NDIM + i];
  __syncthreads();
  const float* Pb = P1 + (size_t)b * MAT;
  float acc = 0.f;
#pragma unroll 8
  for (int k = 0; k < NDIM; ++k) acc += Pb[(size_t)k * NDIM + i] * ws_s[k];
  out[b * NDIM + i] = c[b * NDIM + i] + acc;
}

// =====================================================================
extern "C" void kernel_launch(void* const* d_in, const int* in_sizes, int n_in,
                              void* d_out, int out_size, void* d_ws, size_t ws_size,
                              hipStream_t stream) {
  const float* Q = (const float*)d_in[0];
  const float* p = (const float*)d_in[1];
  const float* A = (const float*)d_in[2];
  const float* lb = (const float*)d_in[3];
  const float* ub = (const float*)d_in[4];
  float* out = (float*)d_out;

  float* B0 = (float*)d_ws;              // ATA -> M -> L -> Minv -> S'
  float* B1 = B0 + BATMAT;               // W -> P1
  float* cbuf = B1 + BATMAT;             // [128*512]
  float* dbuf = cbuf + NBATCH * NDIM;    // [128*512]
  float* wbuf = dbuf + NBATCH * NDIM;    // [128*512]
  float* ubuf = wbuf + NBATCH * NDIM;    // [128*512]
  float* rhobuf = ubuf + NBATCH * NDIM;  // [128]

  // zero W buffer (upper triangle must be 0) and the w/u iteration state
  hipMemsetAsync(B1, 0, BATMAT * sizeof(float), stream);
  hipMemsetAsync(wbuf, 0, 2 * NBATCH * NDIM * sizeof(float), stream);

  // 1) ATA = A^T A -> B0
  gemm512b<0, 0><<<dim3(4, 4, NBATCH), 256, 0, stream>>>(A, A, B0, nullptr);
  // 2) rho[b]
  norms_rho<<<NBATCH, 512, 0, stream>>>(Q, B0, rhobuf);
  // 3) M = Q + rho*ATA + sigma*I (in place on B0)
  form_m<<<2048, 256, 0, stream>>>(Q, rhobuf, B0);
  // 4) Blocked parallel Cholesky: B0 lower = L
  for (int p8 = 0; p8 < 8; ++p8) {
    chol_diag_panel<<<NBATCH, 256, 0, stream>>>(B0, p8);
    const int r = 7 - p8;
    if (r > 0) chol_syrk<<<dim3(r * (r + 1) / 2, NBATCH), 256, 0, stream>>>(B0, p8);
  }
  // 5) W = L^{-1} -> B1
  trinv_diag<<<NBATCH, 256, 0, stream>>>(B0, B1);
  trinv_offdiag<<<dim3(15, NBATCH), 256, 0, stream>>>(B0, B1);
  // 6) Minv = W^T W -> B0 (L dead)
  gemm512b<0, 0><<<dim3(4, 4, NBATCH), 256, 0, stream>>>(B1, B1, B0, nullptr);
  // 7) c = -Minv p
  cvec_kernel<<<NBATCH, 512, 0, stream>>>(B0, p, cbuf);
  // 8) P1 = rho * A * Minv -> B1 (W dead)
  gemm512b<1, 0><<<dim3(4, 4, NBATCH), 256, 0, stream>>>(A, B0, B1, rhobuf);
  // 9) d = A*c
  dvec_kernel<<<NBATCH, 512, 0, stream>>>(A, cbuf, dbuf);
  // 10) S' = P1 * A^T -> B0 (Minv dead; cvec already computed)
  gemm512b<1, 1><<<dim3(4, 4, NBATCH), 256, 0, stream>>>(B1, A, B0, nullptr);
  // 11) 49 y-space ADMM iterations (x_50 uses w_49)
  for (int it = 0; it < 49; ++it)
    admm_step<<<2 * NBATCH, 512, 0, stream>>>(B0, dbuf, lb, ub, wbuf, ubuf);
  // 12) x = c + P1^T w_49
  final_x<<<NBATCH, 512, 0, stream>>>(B1, cbuf, wbuf, out);
}

// Round 4
// 4399.103 us; speedup vs baseline: 1.4168x; 1.4168x over previous
//
#include <hip/hip_runtime.h>

#define NBATCH 128
#define NDIM 512
static constexpr size_t MAT = (size_t)NDIM * NDIM;      // 262144
static constexpr size_t BATMAT = (size_t)NBATCH * MAT;  // 33554432 floats
#define SIGMA_F 1e-6f

// =====================================================================
// GEMM 128x128 tile, 8x8 per thread: C[i][j] = alpha*sum_k OpA(k,i)*OpB(k,j)
//   OpA(k,i) = TA ? A[i*N+k] : A[k*N+i]
//   OpB(k,j) = TB ? B[j*N+k] : B[k*N+j]
// grid (4,4,NBATCH), 256 threads.
// =====================================================================
template <int TA, int TB>
__global__ __launch_bounds__(256) void gemm512b(const float* __restrict__ Ag,
                                                const float* __restrict__ Bg,
                                                float* __restrict__ Cg,
                                                const float* __restrict__ alphaPtr) {
  const int b = blockIdx.z;
  const float* Ab = Ag + (size_t)b * MAT;
  const float* Bb = Bg + (size_t)b * MAT;
  float* Cb = Cg + (size_t)b * MAT;
  const int i0 = blockIdx.y * 128, j0 = blockIdx.x * 128;
  __shared__ float As[32][132];
  __shared__ float Bs[32][132];
  const int tid = threadIdx.x;
  const int tx = tid & 15, ty = tid >> 4;
  float acc[2][2][4][4] = {};
  for (int k0 = 0; k0 < NDIM; k0 += 32) {
    if (TA == 0) {
      const int kk = tid >> 5, c4 = (tid & 31) << 2;
#pragma unroll
      for (int pp = 0; pp < 4; ++pp) {
        float4 v = *reinterpret_cast<const float4*>(&Ab[(size_t)(k0 + kk + 8 * pp) * NDIM + i0 + c4]);
        *reinterpret_cast<float4*>(&As[kk + 8 * pp][c4]) = v;
      }
    } else {
      const int m = tid >> 3, kq = (tid & 7) << 2;
#pragma unroll
      for (int pp = 0; pp < 4; ++pp) {
        float4 v = *reinterpret_cast<const float4*>(&Ab[(size_t)(i0 + m + 32 * pp) * NDIM + k0 + kq]);
        As[kq + 0][m + 32 * pp] = v.x;
        As[kq + 1][m + 32 * pp] = v.y;
        As[kq + 2][m + 32 * pp] = v.z;
        As[kq + 3][m + 32 * pp] = v.w;
      }
    }
    if (TB == 0) {
      const int kk = tid >> 5, c4 = (tid & 31) << 2;
#pragma unroll
      for (int pp = 0; pp < 4; ++pp) {
        float4 v = *reinterpret_cast<const float4*>(&Bb[(size_t)(k0 + kk + 8 * pp) * NDIM + j0 + c4]);
        *reinterpret_cast<float4*>(&Bs[kk + 8 * pp][c4]) = v;
      }
    } else {
      const int m = tid >> 3, kq = (tid & 7) << 2;
#pragma unroll
      for (int pp = 0; pp < 4; ++pp) {
        float4 v = *reinterpret_cast<const float4*>(&Bb[(size_t)(j0 + m + 32 * pp) * NDIM + k0 + kq]);
        Bs[kq + 0][m + 32 * pp] = v.x;
        Bs[kq + 1][m + 32 * pp] = v.y;
        Bs[kq + 2][m + 32 * pp] = v.z;
        Bs[kq + 3][m + 32 * pp] = v.w;
      }
    }
    __syncthreads();
#pragma unroll
    for (int kk = 0; kk < 32; ++kk) {
      float4 a0 = *reinterpret_cast<const float4*>(&As[kk][ty << 2]);
      float4 a1 = *reinterpret_cast<const float4*>(&As[kk][64 + (ty << 2)]);
      float4 b0 = *reinterpret_cast<const float4*>(&Bs[kk][tx << 2]);
      float4 b1 = *reinterpret_cast<const float4*>(&Bs[kk][64 + (tx << 2)]);
      const float ar[2][4] = {{a0.x, a0.y, a0.z, a0.w}, {a1.x, a1.y, a1.z, a1.w}};
      const float br[2][4] = {{b0.x, b0.y, b0.z, b0.w}, {b1.x, b1.y, b1.z, b1.w}};
#pragma unroll
      for (int ri = 0; ri < 2; ++ri)
#pragma unroll
        for (int ci = 0; ci < 2; ++ci)
#pragma unroll
          for (int r = 0; r < 4; ++r)
#pragma unroll
            for (int c = 0; c < 4; ++c)
              acc[ri][ci][r][c] += ar[ri][r] * br[ci][c];
    }
    __syncthreads();
  }
  const float alpha = alphaPtr ? alphaPtr[b] : 1.0f;
#pragma unroll
  for (int ri = 0; ri < 2; ++ri)
#pragma unroll
    for (int r = 0; r < 4; ++r) {
      const int gi = i0 + ri * 64 + (ty << 2) + r;
#pragma unroll
      for (int ci = 0; ci < 2; ++ci) {
        float4 o = make_float4(alpha * acc[ri][ci][r][0], alpha * acc[ri][ci][r][1],
                               alpha * acc[ri][ci][r][2], alpha * acc[ri][ci][r][3]);
        *reinterpret_cast<float4*>(&Cb[(size_t)gi * NDIM + j0 + ci * 64 + (tx << 2)]) = o;
      }
    }
}

// =====================================================================
// rho[b] = clip( ||Q||_F / ||ATA||_F , 1e-6, 1e6 )
// =====================================================================
__global__ __launch_bounds__(512) void norms_rho(const float* __restrict__ Q,
                                                 const float* __restrict__ ATA,
                                                 float* __restrict__ rho) {
  const int b = blockIdx.x;
  const int tid = threadIdx.x;
  const float* Qb = Q + (size_t)b * MAT;
  const float* Tb = ATA + (size_t)b * MAT;
  double sq = 0.0, st = 0.0;
  for (int e = tid; e < (int)MAT; e += 512) {
    float q = Qb[e];
    float t = Tb[e];
    sq += (double)q * q;
    st += (double)t * t;
  }
  __shared__ double s1[512];
  __shared__ double s2[512];
  s1[tid] = sq;
  s2[tid] = st;
  __syncthreads();
  for (int h = 256; h > 0; h >>= 1) {
    if (tid < h) {
      s1[tid] += s1[tid + h];
      s2[tid] += s2[tid + h];
    }
    __syncthreads();
  }
  if (tid == 0) {
    double r = sqrt(s1[0]) / sqrt(s2[0]);
    r = fmin(fmax(r, 1e-6), 1e6);
    rho[b] = (float)r;
  }
}

// =====================================================================
// M = Q + rho*ATA + sigma*I   (in place on the ATA buffer)
// =====================================================================
__global__ void form_m(const float* __restrict__ Q, const float* __restrict__ rho,
                       float* __restrict__ M) {
  size_t stride = (size_t)gridDim.x * blockDim.x;
  for (size_t e = (size_t)blockIdx.x * blockDim.x + threadIdx.x; e < BATMAT; e += stride) {
    int b = (int)(e >> 18);
    int ij = (int)(e & (MAT - 1));
    int i = ij >> 9, j = ij & 511;
    float v = Q[e] + rho[b] * M[e];
    if (i == j) v += SIGMA_F;
    M[e] = v;
  }
}

// =====================================================================
// Blocked Gauss-Jordan inversion (SPD, no pivoting), NB=64, 8 steps.
// Step p:
//   gj_pivot : snapshot col-panel -> Csave; S = inv(M[p][p]) (register GJ);
//              M[p][p] = S
//   gj_row   : M[p][jt] = S * M[p][jt]           (jt != p, parallel)
//   gj_update: M[it][jt] -= Csave[it] * M[p][jt] (it != p, all jt;
//              jt==p tile: M[it][p] = -Csave[it]*S)
// =====================================================================
__global__ __launch_bounds__(256) void gj_pivot(float* __restrict__ Mg,
                                                float* __restrict__ Csave, int p) {
  const int b = blockIdx.x;
  float* M = Mg + (size_t)b * MAT;
  float* Cs = Csave + (size_t)b * ((size_t)NDIM * 64);
  const int tid = threadIdx.x;
  const int k0 = p * 64;
  // 1) snapshot the whole pivot column panel (512 x 64)
  for (int e = tid; e < 512 * 16; e += 256) {
    int r = e >> 4, c4 = (e & 15) << 2;
    float4 v = *reinterpret_cast<const float4*>(&M[(size_t)r * NDIM + k0 + c4]);
    *reinterpret_cast<float4*>(&Cs[r * 64 + c4]) = v;
  }
  // 2) register-tiled GJ inverse of the 64x64 pivot block
  //    thread t owns row r = t&63, cols cb..cb+15 (cb = (t>>6)*16)
  const int r = tid & 63, cb = (tid >> 6) << 4;
  float dreg[16];
#pragma unroll
  for (int q = 0; q < 16; ++q) dreg[q] = M[(size_t)(k0 + r) * NDIM + k0 + cb + q];
  __shared__ float rowb[64];
  __shared__ float colb[64];
  for (int j = 0; j < 64; ++j) {
    const int jc = j - cb;
    if (jc >= 0 && jc < 16) colb[r] = dreg[jc];
    if (r == j) {
#pragma unroll
      for (int q = 0; q < 16; ++q) rowb[cb + q] = dreg[q];
    }
    __syncthreads();
    const float piv = 1.0f / rowb[j];
    const float cj = colb[r];
    if (r == j) {
#pragma unroll
      for (int q = 0; q < 16; ++q) dreg[q] = (cb + q == j) ? piv : rowb[cb + q] * piv;
    } else {
#pragma unroll
      for (int q = 0; q < 16; ++q) {
        float rv = rowb[cb + q] * piv;
        dreg[q] = (cb + q == j) ? (-cj * piv) : fmaf(-cj, rv, dreg[q]);
      }
    }
    __syncthreads();
  }
  // 3) write S back into the pivot tile
#pragma unroll
  for (int q = 0; q < 16; ++q) M[(size_t)(k0 + r) * NDIM + k0 + cb + q] = dreg[q];
}

// grid (7, NBATCH): transform row-panel tile jt (skipping p)
__global__ __launch_bounds__(256) void gj_row(float* __restrict__ Mg, int p) {
  const int b = blockIdx.y;
  const int jt = blockIdx.x + (blockIdx.x >= p ? 1 : 0);
  float* M = Mg + (size_t)b * MAT;
  const int k0 = p * 64, j0 = jt * 64;
  __shared__ float Ss[64][68];  // S (symmetric) -> used as [m][r]
  __shared__ float Rs[64][68];  // old row tile, [m][c]
  const int tid = threadIdx.x;
  for (int e = tid; e < 1024; e += 256) {
    int rr = e >> 4, c4 = (e & 15) << 2;
    *reinterpret_cast<float4*>(&Ss[rr][c4]) =
        *reinterpret_cast<const float4*>(&M[(size_t)(k0 + rr) * NDIM + k0 + c4]);
    *reinterpret_cast<float4*>(&Rs[rr][c4]) =
        *reinterpret_cast<const float4*>(&M[(size_t)(k0 + rr) * NDIM + j0 + c4]);
  }
  __syncthreads();
  const int tx = tid & 15, ty = tid >> 4;
  float acc[4][4] = {};
#pragma unroll 16
  for (int m = 0; m < 64; ++m) {
    float4 a = *reinterpret_cast<const float4*>(&Ss[m][ty << 2]);
    float4 bv = *reinterpret_cast<const float4*>(&Rs[m][tx << 2]);
    acc[0][0] += a.x * bv.x; acc[0][1] += a.x * bv.y; acc[0][2] += a.x * bv.z; acc[0][3] += a.x * bv.w;
    acc[1][0] += a.y * bv.x; acc[1][1] += a.y * bv.y; acc[1][2] += a.y * bv.z; acc[1][3] += a.y * bv.w;
    acc[2][0] += a.z * bv.x; acc[2][1] += a.z * bv.y; acc[2][2] += a.z * bv.z; acc[2][3] += a.z * bv.w;
    acc[3][0] += a.w * bv.x; acc[3][1] += a.w * bv.y; acc[3][2] += a.w * bv.z; acc[3][3] += a.w * bv.w;
  }
#pragma unroll
  for (int rr = 0; rr < 4; ++rr) {
    float4 o = make_float4(acc[rr][0], acc[rr][1], acc[rr][2], acc[rr][3]);
    *reinterpret_cast<float4*>(&M[(size_t)(k0 + (ty << 2) + rr) * NDIM + j0 + (tx << 2)]) = o;
  }
}

// grid (8, 7, NBATCH): jt = x, it = y (skipping p), b = z
__global__ __launch_bounds__(256) void gj_update(float* __restrict__ Mg,
                                                 const float* __restrict__ Csave, int p) {
  const int b = blockIdx.z;
  const int jt = blockIdx.x;
  const int it = blockIdx.y + (blockIdx.y >= p ? 1 : 0);
  float* M = Mg + (size_t)b * MAT;
  const float* Cs = Csave + (size_t)b * ((size_t)NDIM * 64);
  const int k0 = p * 64, i0 = it * 64, j0 = jt * 64;
  __shared__ float Ts[64][68];  // Ts[m][r] = T[r][m]  (old col-panel tile, transposed)
  __shared__ float Rs[64][68];  // Rs[m][c]            (new row-panel tile)
  const int tid = threadIdx.x;
  {
    const int rr = tid >> 2, mq = (tid & 3) << 4;
#pragma unroll
    for (int q = 0; q < 4; ++q) {
      float4 v = *reinterpret_cast<const float4*>(&Cs[(i0 + rr) * 64 + mq + q * 4]);
      Ts[mq + q * 4 + 0][rr] = v.x;
      Ts[mq + q * 4 + 1][rr] = v.y;
      Ts[mq + q * 4 + 2][rr] = v.z;
      Ts[mq + q * 4 + 3][rr] = v.w;
    }
  }
  for (int e = tid; e < 1024; e += 256) {
    int rr = e >> 4, c4 = (e & 15) << 2;
    *reinterpret_cast<float4*>(&Rs[rr][c4]) =
        *reinterpret_cast<const float4*>(&M[(size_t)(k0 + rr) * NDIM + j0 + c4]);
  }
  __syncthreads();
  const int tx = tid & 15, ty = tid >> 4;
  float acc[4][4] = {};
#pragma unroll 16
  for (int m = 0; m < 64; ++m) {
    float4 a = *reinterpret_cast<const float4*>(&Ts[m][ty << 2]);
    float4 bv = *reinterpret_cast<const float4*>(&Rs[m][tx << 2]);
    acc[0][0] += a.x * bv.x; acc[0][1] += a.x * bv.y; acc[0][2] += a.x * bv.z; acc[0][3] += a.x * bv.w;
    acc[1][0] += a.y * bv.x; acc[1][1] += a.y * bv.y; acc[1][2] += a.y * bv.z; acc[1][3] += a.y * bv.w;
    acc[2][0] += a.z * bv.x; acc[2][1] += a.z * bv.y; acc[2][2] += a.z * bv.z; acc[2][3] += a.z * bv.w;
    acc[3][0] += a.w * bv.x; acc[3][1] += a.w * bv.y; acc[3][2] += a.w * bv.z; acc[3][3] += a.w * bv.w;
  }
  if (jt == p) {
#pragma unroll
    for (int rr = 0; rr < 4; ++rr) {
      float4 o = make_float4(-acc[rr][0], -acc[rr][1], -acc[rr][2], -acc[rr][3]);
      *reinterpret_cast<float4*>(&M[(size_t)(i0 + (ty << 2) + rr) * NDIM + j0 + (tx << 2)]) = o;
    }
  } else {
#pragma unroll
    for (int rr = 0; rr < 4; ++rr) {
      float* dst = &M[(size_t)(i0 + (ty << 2) + rr) * NDIM + j0 + (tx << 2)];
      float4 cur = *reinterpret_cast<const float4*>(dst);
      cur.x -= acc[rr][0];
      cur.y -= acc[rr][1];
      cur.z -= acc[rr][2];
      cur.w -= acc[rr][3];
      *reinterpret_cast<float4*>(dst) = cur;
    }
  }
}

// =====================================================================
// c = -Minv * p
// =====================================================================
__global__ __launch_bounds__(512) void cvec_kernel(const float* __restrict__ Minv,
                                                   const float* __restrict__ p,
                                                   float* __restrict__ c) {
  const int b = blockIdx.x, i = threadIdx.x;
  __shared__ float ps[512];
  ps[i] = p[b * NDIM + i];
  __syncthreads();
  const float* Mb = Minv + (size_t)b * MAT;
  float acc = 0.f;
#pragma unroll 8
  for (int m = 0; m < NDIM; ++m) acc += Mb[m * NDIM + i] * ps[m];
  c[b * NDIM + i] = -acc;
}

// =====================================================================
// d = A * c   (wave row-dots)
// =====================================================================
__global__ __launch_bounds__(512) void dvec_kernel(const float* __restrict__ Ain,
                                                   const float* __restrict__ c,
                                                   float* __restrict__ d) {
  const int b = blockIdx.x, i = threadIdx.x;
  __shared__ float cs[512];
  cs[i] = c[b * NDIM + i];
  __syncthreads();
  const int wv = i >> 6, ln = i & 63;
  const float* Ab = Ain + (size_t)b * MAT;
  for (int q = 0; q < 64; ++q) {
    const int j = wv * 64 + q;
    const float* Arow = Ab + (size_t)j * NDIM;
    float s = 0.f;
#pragma unroll
    for (int h = 0; h < 8; ++h) s += Arow[h * 64 + ln] * cs[h * 64 + ln];
    for (int off = 32; off > 0; off >>= 1) s += __shfl_down(s, off);
    if (ln == 0) d[b * NDIM + j] = s;
  }
}

// =====================================================================
// One ADMM iteration in y-space:  y = d + S'w;  z=clip(y+u); u+=y-z; w=z-u
// grid: 256 blocks (2 per batch, j-halved), 512 threads.
// =====================================================================
__global__ __launch_bounds__(512) void admm_step(const float* __restrict__ S,
                                                 const float* __restrict__ dvec,
                                                 const float* __restrict__ lb,
                                                 const float* __restrict__ ub,
                                                 float* __restrict__ wbuf,
                                                 float* __restrict__ ubuf) {
  const int blk = blockIdx.x;
  const int b = blk >> 1, h = blk & 1;
  const int t = threadIdx.x;
  __shared__ float ws_s[512];
  __shared__ float4 part[512];
  ws_s[t] = wbuf[b * NDIM + t];
  __syncthreads();
  const int j4 = t & 63;
  const int ks = t >> 6;
  const float4* Srow = reinterpret_cast<const float4*>(S + (size_t)b * MAT) +
                       (size_t)(ks * 64) * 128 + h * 64 + j4;
  float4 acc = make_float4(0.f, 0.f, 0.f, 0.f);
#pragma unroll 8
  for (int k = 0; k < 64; ++k) {
    float w = ws_s[ks * 64 + k];
    float4 s = Srow[(size_t)k * 128];
    acc.x += s.x * w;
    acc.y += s.y * w;
    acc.z += s.z * w;
    acc.w += s.w * w;
  }
  part[t] = acc;
  __syncthreads();
  if (t < 64) {
    float4 y = part[t];
#pragma unroll
    for (int s = 1; s < 8; ++s) {
      float4 q = part[s * 64 + t];
      y.x += q.x; y.y += q.y; y.z += q.z; y.w += q.w;
    }
    const size_t off = (size_t)b * NDIM + h * 256 + t * 4;
    float4 dv = *reinterpret_cast<const float4*>(dvec + off);
    float4 uv = *reinterpret_cast<const float4*>(ubuf + off);
    float4 lbv = *reinterpret_cast<const float4*>(lb + off);
    float4 ubv = *reinterpret_cast<const float4*>(ub + off);
    y.x += dv.x; y.y += dv.y; y.z += dv.z; y.w += dv.w;
    float4 zv, wv;
    zv.x = fminf(fmaxf(y.x + uv.x, lbv.x), ubv.x);
    zv.y = fminf(fmaxf(y.y + uv.y, lbv.y), ubv.y);
    zv.z = fminf(fmaxf(y.z + uv.z, lbv.z), ubv.z);
    zv.w = fminf(fmaxf(y.w + uv.w, lbv.w), ubv.w);
    uv.x += y.x - zv.x; uv.y += y.y - zv.y; uv.z += y.z - zv.z; uv.w += y.w - zv.w;
    wv.x = zv.x - uv.x; wv.y = zv.y - uv.y; wv.z = zv.z - uv.z; wv.w = zv.w - uv.w;
    *reinterpret_cast<float4*>(ubuf + off) = uv;
    *reinterpret_cast<float4*>(wbuf + off) = wv;
  }
}

// =====================================================================
// x = c + P1^T w
// =====================================================================
__global__ __launch_bounds__(512) void final_x(const float* __restrict__ P1,
                                               const float* __restrict__ c,
                                               const float* __restrict__ w,
                                               float* __restrict__ out) {
  const int b = blockIdx.x, i = threadIdx.x;
  __shared__ float ws_s[512];
  ws_s[i] = w[b * NDIM + i];
  __syncthreads();
  const float* Pb = P1 + (size_t)b * MAT;
  float acc = 0.f;
#pragma unroll 8
  for (int k = 0; k < NDIM; ++k) acc += Pb[(size_t)k * NDIM + i] * ws_s[k];
  out[b * NDIM + i] = c[b * NDIM + i] + acc;
}

// =====================================================================
extern "C" void kernel_launch(void* const* d_in, const int* in_sizes, int n_in,
                              void* d_out, int out_size, void* d_ws, size_t ws_size,
                              hipStream_t stream) {
  const float* Q = (const float*)d_in[0];
  const float* p = (const float*)d_in[1];
  const float* A = (const float*)d_in[2];
  const float* lb = (const float*)d_in[3];
  const float* ub = (const float*)d_in[4];
  float* out = (float*)d_out;

  float* B0 = (float*)d_ws;              // ATA -> M -> Minv -> S'
  float* B1 = B0 + BATMAT;               // GJ col snapshot, then P1
  float* cbuf = B1 + BATMAT;             // [128*512]
  float* dbuf = cbuf + NBATCH * NDIM;    // [128*512]
  float* wbuf = dbuf + NBATCH * NDIM;    // [128*512]
  float* ubuf = wbuf + NBATCH * NDIM;    // [128*512]
  float* rhobuf = ubuf + NBATCH * NDIM;  // [128]

  // zero the w/u iteration state
  hipMemsetAsync(wbuf, 0, 2 * NBATCH * NDIM * sizeof(float), stream);

  // 1) ATA = A^T A -> B0
  gemm512b<0, 0><<<dim3(4, 4, NBATCH), 256, 0, stream>>>(A, A, B0, nullptr);
  // 2) rho[b]
  norms_rho<<<NBATCH, 512, 0, stream>>>(Q, B0, rhobuf);
  // 3) M = Q + rho*ATA + sigma*I (in place on B0)
  form_m<<<2048, 256, 0, stream>>>(Q, rhobuf, B0);
  // 4) Blocked Gauss-Jordan: B0 = Minv (in place), 8 steps
  for (int p8 = 0; p8 < 8; ++p8) {
    gj_pivot<<<NBATCH, 256, 0, stream>>>(B0, B1, p8);
    gj_row<<<dim3(7, NBATCH), 256, 0, stream>>>(B0, p8);
    gj_update<<<dim3(8, 7, NBATCH), 256, 0, stream>>>(B0, B1, p8);
  }
  // 5) c = -Minv p
  cvec_kernel<<<NBATCH, 512, 0, stream>>>(B0, p, cbuf);
  // 6) P1 = rho * A * Minv -> B1
  gemm512b<1, 0><<<dim3(4, 4, NBATCH), 256, 0, stream>>>(A, B0, B1, rhobuf);
  // 7) d = A*c
  dvec_kernel<<<NBATCH, 512, 0, stream>>>(A, cbuf, dbuf);
  // 8) S' = P1 * A^T -> B0 (Minv dead)
  gemm512b<1, 1><<<dim3(4, 4, NBATCH), 256, 0, stream>>>(B1, A, B0, nullptr);
  // 9) 49 y-space ADMM iterations (x_50 uses w_49)
  for (int it = 0; it < 49; ++it)
    admm_step<<<2 * NBATCH, 512, 0, stream>>>(B0, dbuf, lb, ub, wbuf, ubuf);
  // 10) x = c + P1^T w_49
  final_x<<<NBATCH, 512, 0, stream>>>(B1, cbuf, wbuf, out);
}

// Round 5
// 4113.528 us; speedup vs baseline: 1.5151x; 1.0694x over previous
//
#include <hip/hip_runtime.h>

#define NBATCH 128
#define NDIM 512
static constexpr size_t MAT = (size_t)NDIM * NDIM;      // 262144
static constexpr size_t BATMAT = (size_t)NBATCH * MAT;  // 33554432 floats
#define SIGMA_F 1e-6f

typedef __attribute__((ext_vector_type(8))) short bf16x8;
typedef __attribute__((ext_vector_type(4))) float f32x4;

__device__ inline ushort f2bf_rne(float x) {
  unsigned u = __builtin_bit_cast(unsigned, x);
  unsigned r = (u + 0x7fffu + ((u >> 16) & 1u)) >> 16;
  return (ushort)r;
}
__device__ inline void splitf(float x, ushort& h, ushort& l) {
  h = f2bf_rne(x);
  float hf = __builtin_bit_cast(float, (unsigned)((unsigned)h << 16));
  l = f2bf_rne(x - hf);
}

// =====================================================================
// Split-bf16 MFMA GEMM, 128x128 tile, 4 waves, BK=32.
//   C[i][j] = alpha * sum_k OpA(i,k)*OpB(j,k)
//   TR=0: operand stored row-major [m][k] (direct stage, vectorized)
//   TR=1: operand stored [k][m] (transpose stage, scalar stores)
// Uses: ATA: <1,1>(A,A); T1 = A*Minv: <0,0>(A,Minv) [Minv symmetric];
//       S' = rho*T1*A^T: <0,0>(T1,A).
// =====================================================================
template <int TRA, int TRB>
__global__ __launch_bounds__(256) void gemm_mfma(const float* __restrict__ Ag,
                                                 const float* __restrict__ Bg,
                                                 float* __restrict__ Cg,
                                                 const float* __restrict__ alphaPtr) {
  const int b = blockIdx.z;
  const float* Ab = Ag + (size_t)b * MAT;
  const float* Bb = Bg + (size_t)b * MAT;
  float* Cb = Cg + (size_t)b * MAT;
  const int i0 = blockIdx.y * 128, j0 = blockIdx.x * 128;
  __shared__ __align__(16) ushort Ah[128][40];
  __shared__ __align__(16) ushort Al[128][40];
  __shared__ __align__(16) ushort Bh[128][40];
  __shared__ __align__(16) ushort Bl[128][40];
  const int tid = threadIdx.x;
  const int lane = tid & 63, wid = tid >> 6;
  const int wr = wid >> 1, wc = wid & 1;
  const int fr = lane & 15, fg = lane >> 4;
  f32x4 acc[4][4];
#pragma unroll
  for (int m = 0; m < 4; ++m)
#pragma unroll
    for (int n = 0; n < 4; ++n) acc[m][n] = (f32x4){0.f, 0.f, 0.f, 0.f};

  for (int k0 = 0; k0 < NDIM; k0 += 32) {
    // ---- stage A ----
    if (TRA == 0) {
      const int srow = tid >> 3, skk = (tid & 7) << 2;
#pragma unroll
      for (int pp = 0; pp < 4; ++pp) {
        const int row = srow + 32 * pp;
        float4 v = *reinterpret_cast<const float4*>(&Ab[(size_t)(i0 + row) * NDIM + k0 + skk]);
        ushort4 h, l;
        splitf(v.x, h.x, l.x); splitf(v.y, h.y, l.y);
        splitf(v.z, h.z, l.z); splitf(v.w, h.w, l.w);
        *reinterpret_cast<ushort4*>(&Ah[row][skk]) = h;
        *reinterpret_cast<ushort4*>(&Al[row][skk]) = l;
      }
    } else {
      const int skk = tid >> 5, sm4 = (tid & 31) << 2;
#pragma unroll
      for (int pp = 0; pp < 4; ++pp) {
        const int kk = skk + 8 * pp;
        float4 v = *reinterpret_cast<const float4*>(&Ab[(size_t)(k0 + kk) * NDIM + i0 + sm4]);
        ushort h, l;
        splitf(v.x, h, l); Ah[sm4 + 0][kk] = h; Al[sm4 + 0][kk] = l;
        splitf(v.y, h, l); Ah[sm4 + 1][kk] = h; Al[sm4 + 1][kk] = l;
        splitf(v.z, h, l); Ah[sm4 + 2][kk] = h; Al[sm4 + 2][kk] = l;
        splitf(v.w, h, l); Ah[sm4 + 3][kk] = h; Al[sm4 + 3][kk] = l;
      }
    }
    // ---- stage B ----
    if (TRB == 0) {
      const int srow = tid >> 3, skk = (tid & 7) << 2;
#pragma unroll
      for (int pp = 0; pp < 4; ++pp) {
        const int row = srow + 32 * pp;
        float4 v = *reinterpret_cast<const float4*>(&Bb[(size_t)(j0 + row) * NDIM + k0 + skk]);
        ushort4 h, l;
        splitf(v.x, h.x, l.x); splitf(v.y, h.y, l.y);
        splitf(v.z, h.z, l.z); splitf(v.w, h.w, l.w);
        *reinterpret_cast<ushort4*>(&Bh[row][skk]) = h;
        *reinterpret_cast<ushort4*>(&Bl[row][skk]) = l;
      }
    } else {
      const int skk = tid >> 5, sm4 = (tid & 31) << 2;
#pragma unroll
      for (int pp = 0; pp < 4; ++pp) {
        const int kk = skk + 8 * pp;
        float4 v = *reinterpret_cast<const float4*>(&Bb[(size_t)(k0 + kk) * NDIM + j0 + sm4]);
        ushort h, l;
        splitf(v.x, h, l); Bh[sm4 + 0][kk] = h; Bl[sm4 + 0][kk] = l;
        splitf(v.y, h, l); Bh[sm4 + 1][kk] = h; Bl[sm4 + 1][kk] = l;
        splitf(v.z, h, l); Bh[sm4 + 2][kk] = h; Bl[sm4 + 2][kk] = l;
        splitf(v.w, h, l); Bh[sm4 + 3][kk] = h; Bl[sm4 + 3][kk] = l;
      }
    }
    __syncthreads();
    // ---- compute: 16 frag-pairs x 3 split MFMAs ----
    bf16x8 ah[4], al4[4], bh4[4], bl4[4];
#pragma unroll
    for (int m = 0; m < 4; ++m) {
      const int row = wr * 64 + m * 16 + fr;
      ah[m] = *reinterpret_cast<const bf16x8*>(&Ah[row][fg * 8]);
      al4[m] = *reinterpret_cast<const bf16x8*>(&Al[row][fg * 8]);
    }
#pragma unroll
    for (int n = 0; n < 4; ++n) {
      const int row = wc * 64 + n * 16 + fr;
      bh4[n] = *reinterpret_cast<const bf16x8*>(&Bh[row][fg * 8]);
      bl4[n] = *reinterpret_cast<const bf16x8*>(&Bl[row][fg * 8]);
    }
#pragma unroll
    for (int m = 0; m < 4; ++m)
#pragma unroll
      for (int n = 0; n < 4; ++n) {
        acc[m][n] = __builtin_amdgcn_mfma_f32_16x16x32_bf16(ah[m], bh4[n], acc[m][n], 0, 0, 0);
        acc[m][n] = __builtin_amdgcn_mfma_f32_16x16x32_bf16(ah[m], bl4[n], acc[m][n], 0, 0, 0);
        acc[m][n] = __builtin_amdgcn_mfma_f32_16x16x32_bf16(al4[m], bh4[n], acc[m][n], 0, 0, 0);
      }
    __syncthreads();
  }
  const float alpha = alphaPtr ? alphaPtr[b] : 1.0f;
#pragma unroll
  for (int m = 0; m < 4; ++m)
#pragma unroll
    for (int n = 0; n < 4; ++n) {
      const int col = j0 + wc * 64 + n * 16 + fr;
      const int rowb = i0 + wr * 64 + m * 16 + fg * 4;
#pragma unroll
      for (int q = 0; q < 4; ++q)
        Cb[(size_t)(rowb + q) * NDIM + col] = alpha * acc[m][n][q];
    }
}

// =====================================================================
// rho[b] = clip( ||Q||_F / ||ATA||_F , 1e-6, 1e6 )
// =====================================================================
__global__ __launch_bounds__(512) void norms_rho(const float* __restrict__ Q,
                                                 const float* __restrict__ ATA,
                                                 float* __restrict__ rho) {
  const int b = blockIdx.x;
  const int tid = threadIdx.x;
  const float* Qb = Q + (size_t)b * MAT;
  const float* Tb = ATA + (size_t)b * MAT;
  double sq = 0.0, st = 0.0;
  for (int e = tid; e < (int)MAT; e += 512) {
    float q = Qb[e];
    float t = Tb[e];
    sq += (double)q * q;
    st += (double)t * t;
  }
  __shared__ double s1[512];
  __shared__ double s2[512];
  s1[tid] = sq;
  s2[tid] = st;
  __syncthreads();
  for (int h = 256; h > 0; h >>= 1) {
    if (tid < h) {
      s1[tid] += s1[tid + h];
      s2[tid] += s2[tid + h];
    }
    __syncthreads();
  }
  if (tid == 0) {
    double r = sqrt(s1[0]) / sqrt(s2[0]);
    r = fmin(fmax(r, 1e-6), 1e6);
    rho[b] = (float)r;
  }
}

// =====================================================================
// M = Q + rho*ATA + sigma*I   (in place on the ATA buffer)
// =====================================================================
__global__ void form_m(const float* __restrict__ Q, const float* __restrict__ rho,
                       float* __restrict__ M) {
  size_t stride = (size_t)gridDim.x * blockDim.x;
  for (size_t e = (size_t)blockIdx.x * blockDim.x + threadIdx.x; e < BATMAT; e += stride) {
    int b = (int)(e >> 18);
    int ij = (int)(e & (MAT - 1));
    int i = ij >> 9, j = ij & 511;
    float v = Q[e] + rho[b] * M[e];
    if (i == j) v += SIGMA_F;
    M[e] = v;
  }
}

// =====================================================================
// Blocked Gauss-Jordan inversion (SPD, no pivoting), NB=64, 8 steps.
// =====================================================================
__global__ __launch_bounds__(256) void gj_pivot(float* __restrict__ Mg,
                                                float* __restrict__ Csave, int p) {
  const int b = blockIdx.x;
  float* M = Mg + (size_t)b * MAT;
  float* Cs = Csave + (size_t)b * ((size_t)NDIM * 64);
  const int tid = threadIdx.x;
  const int k0 = p * 64;
  for (int e = tid; e < 512 * 16; e += 256) {
    int r = e >> 4, c4 = (e & 15) << 2;
    float4 v = *reinterpret_cast<const float4*>(&M[(size_t)r * NDIM + k0 + c4]);
    *reinterpret_cast<float4*>(&Cs[r * 64 + c4]) = v;
  }
  const int r = tid & 63, cb = (tid >> 6) << 4;
  float dreg[16];
#pragma unroll
  for (int q = 0; q < 16; ++q) dreg[q] = M[(size_t)(k0 + r) * NDIM + k0 + cb + q];
  __shared__ float rowb[64];
  __shared__ float colb[64];
  for (int j = 0; j < 64; ++j) {
    const int jc = j - cb;
    if (jc >= 0 && jc < 16) colb[r] = dreg[jc];
    if (r == j) {
#pragma unroll
      for (int q = 0; q < 16; ++q) rowb[cb + q] = dreg[q];
    }
    __syncthreads();
    const float piv = 1.0f / rowb[j];
    const float cj = colb[r];
    if (r == j) {
#pragma unroll
      for (int q = 0; q < 16; ++q) dreg[q] = (cb + q == j) ? piv : rowb[cb + q] * piv;
    } else {
#pragma unroll
      for (int q = 0; q < 16; ++q) {
        float rv = rowb[cb + q] * piv;
        dreg[q] = (cb + q == j) ? (-cj * piv) : fmaf(-cj, rv, dreg[q]);
      }
    }
    __syncthreads();
  }
#pragma unroll
  for (int q = 0; q < 16; ++q) M[(size_t)(k0 + r) * NDIM + k0 + cb + q] = dreg[q];
}

__global__ __launch_bounds__(256) void gj_row(float* __restrict__ Mg, int p) {
  const int b = blockIdx.y;
  const int jt = blockIdx.x + (blockIdx.x >= p ? 1 : 0);
  float* M = Mg + (size_t)b * MAT;
  const int k0 = p * 64, j0 = jt * 64;
  __shared__ float Ss[64][68];
  __shared__ float Rs[64][68];
  const int tid = threadIdx.x;
  for (int e = tid; e < 1024; e += 256) {
    int rr = e >> 4, c4 = (e & 15) << 2;
    *reinterpret_cast<float4*>(&Ss[rr][c4]) =
        *reinterpret_cast<const float4*>(&M[(size_t)(k0 + rr) * NDIM + k0 + c4]);
    *reinterpret_cast<float4*>(&Rs[rr][c4]) =
        *reinterpret_cast<const float4*>(&M[(size_t)(k0 + rr) * NDIM + j0 + c4]);
  }
  __syncthreads();
  const int tx = tid & 15, ty = tid >> 4;
  float acc[4][4] = {};
#pragma unroll 16
  for (int m = 0; m < 64; ++m) {
    float4 a = *reinterpret_cast<const float4*>(&Ss[m][ty << 2]);
    float4 bv = *reinterpret_cast<const float4*>(&Rs[m][tx << 2]);
    acc[0][0] += a.x * bv.x; acc[0][1] += a.x * bv.y; acc[0][2] += a.x * bv.z; acc[0][3] += a.x * bv.w;
    acc[1][0] += a.y * bv.x; acc[1][1] += a.y * bv.y; acc[1][2] += a.y * bv.z; acc[1][3] += a.y * bv.w;
    acc[2][0] += a.z * bv.x; acc[2][1] += a.z * bv.y; acc[2][2] += a.z * bv.z; acc[2][3] += a.z * bv.w;
    acc[3][0] += a.w * bv.x; acc[3][1] += a.w * bv.y; acc[3][2] += a.w * bv.z; acc[3][3] += a.w * bv.w;
  }
#pragma unroll
  for (int rr = 0; rr < 4; ++rr) {
    float4 o = make_float4(acc[rr][0], acc[rr][1], acc[rr][2], acc[rr][3]);
    *reinterpret_cast<float4*>(&M[(size_t)(k0 + (ty << 2) + rr) * NDIM + j0 + (tx << 2)]) = o;
  }
}

__global__ __launch_bounds__(256) void gj_update(float* __restrict__ Mg,
                                                 const float* __restrict__ Csave, int p) {
  const int b = blockIdx.z;
  const int jt = blockIdx.x;
  const int it = blockIdx.y + (blockIdx.y >= p ? 1 : 0);
  float* M = Mg + (size_t)b * MAT;
  const float* Cs = Csave + (size_t)b * ((size_t)NDIM * 64);
  const int k0 = p * 64, i0 = it * 64, j0 = jt * 64;
  __shared__ float Ts[64][68];
  __shared__ float Rs[64][68];
  const int tid = threadIdx.x;
  {
    const int rr = tid >> 2, mq = (tid & 3) << 4;
#pragma unroll
    for (int q = 0; q < 4; ++q) {
      float4 v = *reinterpret_cast<const float4*>(&Cs[(i0 + rr) * 64 + mq + q * 4]);
      Ts[mq + q * 4 + 0][rr] = v.x;
      Ts[mq + q * 4 + 1][rr] = v.y;
      Ts[mq + q * 4 + 2][rr] = v.z;
      Ts[mq + q * 4 + 3][rr] = v.w;
    }
  }
  for (int e = tid; e < 1024; e += 256) {
    int rr = e >> 4, c4 = (e & 15) << 2;
    *reinterpret_cast<float4*>(&Rs[rr][c4]) =
        *reinterpret_cast<const float4*>(&M[(size_t)(k0 + rr) * NDIM + j0 + c4]);
  }
  __syncthreads();
  const int tx = tid & 15, ty = tid >> 4;
  float acc[4][4] = {};
#pragma unroll 16
  for (int m = 0; m < 64; ++m) {
    float4 a = *reinterpret_cast<const float4*>(&Ts[m][ty << 2]);
    float4 bv = *reinterpret_cast<const float4*>(&Rs[m][tx << 2]);
    acc[0][0] += a.x * bv.x; acc[0][1] += a.x * bv.y; acc[0][2] += a.x * bv.z; acc[0][3] += a.x * bv.w;
    acc[1][0] += a.y * bv.x; acc[1][1] += a.y * bv.y; acc[1][2] += a.y * bv.z; acc[1][3] += a.y * bv.w;
    acc[2][0] += a.z * bv.x; acc[2][1] += a.z * bv.y; acc[2][2] += a.z * bv.z; acc[2][3] += a.z * bv.w;
    acc[3][0] += a.w * bv.x; acc[3][1] += a.w * bv.y; acc[3][2] += a.w * bv.z; acc[3][3] += a.w * bv.w;
  }
  if (jt == p) {
#pragma unroll
    for (int rr = 0; rr < 4; ++rr) {
      float4 o = make_float4(-acc[rr][0], -acc[rr][1], -acc[rr][2], -acc[rr][3]);
      *reinterpret_cast<float4*>(&M[(size_t)(i0 + (ty << 2) + rr) * NDIM + j0 + (tx << 2)]) = o;
    }
  } else {
#pragma unroll
    for (int rr = 0; rr < 4; ++rr) {
      float* dst = &M[(size_t)(i0 + (ty << 2) + rr) * NDIM + j0 + (tx << 2)];
      float4 cur = *reinterpret_cast<const float4*>(dst);
      cur.x -= acc[rr][0];
      cur.y -= acc[rr][1];
      cur.z -= acc[rr][2];
      cur.w -= acc[rr][3];
      *reinterpret_cast<float4*>(dst) = cur;
    }
  }
}

// =====================================================================
// c = -Minv * p
// =====================================================================
__global__ __launch_bounds__(512) void cvec_kernel(const float* __restrict__ Minv,
                                                   const float* __restrict__ p,
                                                   float* __restrict__ c) {
  const int b = blockIdx.x, i = threadIdx.x;
  __shared__ float ps[512];
  ps[i] = p[b * NDIM + i];
  __syncthreads();
  const float* Mb = Minv + (size_t)b * MAT;
  float acc = 0.f;
#pragma unroll 8
  for (int m = 0; m < NDIM; ++m) acc += Mb[m * NDIM + i] * ps[m];
  c[b * NDIM + i] = -acc;
}

// =====================================================================
// d = A * c   (wave row-dots)
// =====================================================================
__global__ __launch_bounds__(512) void dvec_kernel(const float* __restrict__ Ain,
                                                   const float* __restrict__ c,
                                                   float* __restrict__ d) {
  const int b = blockIdx.x, i = threadIdx.x;
  __shared__ float cs[512];
  cs[i] = c[b * NDIM + i];
  __syncthreads();
  const int wv = i >> 6, ln = i & 63;
  const float* Ab = Ain + (size_t)b * MAT;
  for (int q = 0; q < 64; ++q) {
    const int j = wv * 64 + q;
    const float* Arow = Ab + (size_t)j * NDIM;
    float s = 0.f;
#pragma unroll
    for (int h = 0; h < 8; ++h) s += Arow[h * 64 + ln] * cs[h * 64 + ln];
    for (int off = 32; off > 0; off >>= 1) s += __shfl_down(s, off);
    if (ln == 0) d[b * NDIM + j] = s;
  }
}

// =====================================================================
// One ADMM iteration in y-space:  y = d + S'w;  z=clip(y+u); u+=y-z; w=z-u
// grid: 512 blocks (4 per batch, col-quartered), 512 threads.
// =====================================================================
__global__ __launch_bounds__(512) void admm_step(const float* __restrict__ S,
                                                 const float* __restrict__ dvec,
                                                 const float* __restrict__ lb,
                                                 const float* __restrict__ ub,
                                                 float* __restrict__ wbuf,
                                                 float* __restrict__ ubuf) {
  const int blk = blockIdx.x;
  const int b = blk >> 2, qd = blk & 3;
  const int t = threadIdx.x;
  __shared__ float ws_s[512];
  __shared__ float4 part[512];
  ws_s[t] = wbuf[b * NDIM + t];
  __syncthreads();
  const int j4 = t & 31;   // 32 float4 cols = 128 cols in this quarter
  const int ks = t >> 5;   // 16 k-slices of 32
  const float4* Scol = reinterpret_cast<const float4*>(S + (size_t)b * MAT) +
                       (size_t)(ks * 32) * 128 + qd * 32 + j4;
  float4 acc = make_float4(0.f, 0.f, 0.f, 0.f);
#pragma unroll 8
  for (int k = 0; k < 32; ++k) {
    float w = ws_s[ks * 32 + k];
    float4 s = Scol[(size_t)k * 128];
    acc.x += s.x * w;
    acc.y += s.y * w;
    acc.z += s.z * w;
    acc.w += s.w * w;
  }
  part[t] = acc;
  __syncthreads();
  if (t < 32) {
    float4 y = part[t];
#pragma unroll
    for (int s = 1; s < 16; ++s) {
      float4 q = part[s * 32 + t];
      y.x += q.x; y.y += q.y; y.z += q.z; y.w += q.w;
    }
    const size_t off = (size_t)b * NDIM + qd * 128 + t * 4;
    float4 dv = *reinterpret_cast<const float4*>(dvec + off);
    float4 uv = *reinterpret_cast<const float4*>(ubuf + off);
    float4 lbv = *reinterpret_cast<const float4*>(lb + off);
    float4 ubv = *reinterpret_cast<const float4*>(ub + off);
    y.x += dv.x; y.y += dv.y; y.z += dv.z; y.w += dv.w;
    float4 zv, wv;
    zv.x = fminf(fmaxf(y.x + uv.x, lbv.x), ubv.x);
    zv.y = fminf(fmaxf(y.y + uv.y, lbv.y), ubv.y);
    zv.z = fminf(fmaxf(y.z + uv.z, lbv.z), ubv.z);
    zv.w = fminf(fmaxf(y.w + uv.w, lbv.w), ubv.w);
    uv.x += y.x - zv.x; uv.y += y.y - zv.y; uv.z += y.z - zv.z; uv.w += y.w - zv.w;
    wv.x = zv.x - uv.x; wv.y = zv.y - uv.y; wv.z = zv.z - uv.z; wv.w = zv.w - uv.w;
    *reinterpret_cast<float4*>(ubuf + off) = uv;
    *reinterpret_cast<float4*>(wbuf + off) = wv;
  }
}

// =====================================================================
// x = c + rho * T1^T w    (T1 = A*Minv, unscaled)
// =====================================================================
__global__ __launch_bounds__(512) void final_x(const float* __restrict__ T1,
                                               const float* __restrict__ c,
                                               const float* __restrict__ w,
                                               const float* __restrict__ rho,
                                               float* __restrict__ out) {
  const int b = blockIdx.x, i = threadIdx.x;
  __shared__ float ws_s[512];
  ws_s[i] = w[b * NDIM + i];
  __syncthreads();
  const float* Pb = T1 + (size_t)b * MAT;
  float acc = 0.f;
#pragma unroll 8
  for (int k = 0; k < NDIM; ++k) acc += Pb[(size_t)k * NDIM + i] * ws_s[k];
  out[b * NDIM + i] = c[b * NDIM + i] + rho[b] * acc;
}

// =====================================================================
extern "C" void kernel_launch(void* const* d_in, const int* in_sizes, int n_in,
                              void* d_out, int out_size, void* d_ws, size_t ws_size,
                              hipStream_t stream) {
  const float* Q = (const float*)d_in[0];
  const float* p = (const float*)d_in[1];
  const float* A = (const float*)d_in[2];
  const float* lb = (const float*)d_in[3];
  const float* ub = (const float*)d_in[4];
  float* out = (float*)d_out;

  float* B0 = (float*)d_ws;              // ATA -> M -> Minv -> S'
  float* B1 = B0 + BATMAT;               // GJ col snapshot, then T1
  float* cbuf = B1 + BATMAT;             // [128*512]
  float* dbuf = cbuf + NBATCH * NDIM;    // [128*512]
  float* wbuf = dbuf + NBATCH * NDIM;    // [128*512]
  float* ubuf = wbuf + NBATCH * NDIM;    // [128*512]
  float* rhobuf = ubuf + NBATCH * NDIM;  // [128]

  // zero the w/u iteration state
  hipMemsetAsync(wbuf, 0, 2 * NBATCH * NDIM * sizeof(float), stream);

  // 1) ATA = A^T A -> B0   (both operands transposed-staged)
  gemm_mfma<1, 1><<<dim3(4, 4, NBATCH), 256, 0, stream>>>(A, A, B0, nullptr);
  // 2) rho[b]
  norms_rho<<<NBATCH, 512, 0, stream>>>(Q, B0, rhobuf);
  // 3) M = Q + rho*ATA + sigma*I (in place on B0)
  form_m<<<2048, 256, 0, stream>>>(Q, rhobuf, B0);
  // 4) Blocked Gauss-Jordan: B0 = Minv (in place), 8 steps
  for (int p8 = 0; p8 < 8; ++p8) {
    gj_pivot<<<NBATCH, 256, 0, stream>>>(B0, B1, p8);
    gj_row<<<dim3(7, NBATCH), 256, 0, stream>>>(B0, p8);
    gj_update<<<dim3(8, 7, NBATCH), 256, 0, stream>>>(B0, B1, p8);
  }
  // 5) c = -Minv p
  cvec_kernel<<<NBATCH, 512, 0, stream>>>(B0, p, cbuf);
  // 6) T1 = A * Minv -> B1  (B-op direct via Minv symmetry)
  gemm_mfma<0, 0><<<dim3(4, 4, NBATCH), 256, 0, stream>>>(A, B0, B1, nullptr);
  // 7) d = A*c
  dvec_kernel<<<NBATCH, 512, 0, stream>>>(A, cbuf, dbuf);
  // 8) S' = rho * T1 * A^T -> B0 (Minv dead)
  gemm_mfma<0, 0><<<dim3(4, 4, NBATCH), 256, 0, stream>>>(B1, A, B0, rhobuf);
  // 9) 49 y-space ADMM iterations (x_50 uses w_49)
  for (int it = 0; it < 49; ++it)
    admm_step<<<4 * NBATCH, 512, 0, stream>>>(B0, dbuf, lb, ub, wbuf, ubuf);
  // 10) x = c + rho * T1^T w_49
  final_x<<<NBATCH, 512, 0, stream>>>(B1, cbuf, wbuf, rhobuf, out);
}